// Round 2
// baseline (2087.330 us; speedup 1.0000x reference)
//
#include <hip/hip_runtime.h>
#include <cfloat>
#include <cstdint>
#include <cstddef>

// Problem constants
#define M_ROWS 16384
#define NE     8192
#define KD     256

// d_out layout (float elements)
#define OFF_LOSS   0ULL
#define OFF_ZQ     1ULL
#define OFF_PERP   4194305ULL
#define OFF_ONEHOT 4194306ULL
#define OFF_I0     138412034ULL
#define OFF_I1     138428418ULL

// d_ws layout (4-byte units)
#define WS_I0    0        // int[16384]
#define WS_HIST  16384    // int[8192]
#define WS_ENORM 24576    // float[8192]  (np-pairwise-emulated fl32 sum e^2)
#define WS_CNORM 32768    // float[16384] (np-pairwise-emulated fl32 sum z^2 per row)
#define WS_T0SUM 49152    // float
#define WS_TOTAL 49153

// ---------------------------------------------------------------- zero ws
__global__ void zero_ws_kernel(float* __restrict__ ws) {
    int i = blockIdx.x * 256 + threadIdx.x;
    if (i < WS_TOTAL) ws[i] = 0.0f;
}

// ------------------------------------------------- zero one-hot region (537 MB)
__global__ void zero_onehot_kernel(float* __restrict__ out) {
    size_t tidg = (size_t)blockIdx.x * 1024 + threadIdx.x;   // 4096 x 1024
    float4* base = (float4*)(out + OFF_ONEHOT + 2);
    const float4 zz = make_float4(0.f, 0.f, 0.f, 0.f);
#pragma unroll
    for (int i = 0; i < 8; i++) {
        size_t q = tidg + (size_t)i * 4194304ULL;
        if (q < 33554431ULL) base[q] = zz;
    }
    if (tidg == 0) {
        out[OFF_ONEHOT + 0] = 0.f;
        out[OFF_ONEHOT + 1] = 0.f;
        out[OFF_ONEHOT + 134217726ULL] = 0.f;
        out[OFF_ONEHOT + 134217727ULL] = 0.f;
    }
}

// ------------------------------------------------------------------------
// numpy float32 pairwise sum over 256 contiguous elements, emulated exactly:
// n=256 -> pairwise(a,128) + pairwise(a+128,128); n=128 -> 8 accumulators
// r[j] = a[j]; r[j] += a[8i+j] (i=1..15 sequential); combine
// ((r0+r1)+(r2+r3)) + ((r4+r5)+(r6+r7)).
// 16 lanes per row: lane = h*8+j (h=half, j=accum). Squares are staged to LDS
// first so -ffp-contract can't fuse mul+add (numpy rounds the square first).
// ------------------------------------------------------------------------
__device__ __forceinline__ float pairwise16(const float* sq, int lane16) {
    const int h = lane16 >> 3;   // half: 0 -> elements [0,128), 1 -> [128,256)
    const int j = lane16 & 7;    // accumulator index
    float r = sq[h * 128 + j];
#pragma unroll
    for (int i = 1; i < 16; i++) r = r + sq[h * 128 + i * 8 + j];
    // exact combine tree (fl add is commutative, so xor-butterfly matches)
    float s = r + __shfl_xor(r, 1);     // (r0+r1), (r2+r3), ...
    s = s + __shfl_xor(s, 2);           // ((r0+r1)+(r2+r3)), ...
    s = s + __shfl_xor(s, 4);           // full half sum
    s = s + __shfl_xor(s, 8);           // left + right
    return s;
}

// ---------------------------------------------------------------- E_j emulation
__global__ void enorm_kernel(const float* __restrict__ emb, float* __restrict__ enorm) {
    __shared__ float sq[16][257];
    const int tid = threadIdx.x;          // 256
    const int row0 = blockIdx.x * 16;     // 512 blocks
#pragma unroll
    for (int p = 0; p < 4; p++) {
        int q = p * 256 + tid;            // 1024 quads
        int rl = q >> 6, kq = q & 63;
        float4 v = *(const float4*)(emb + (size_t)(row0 + rl) * KD + kq * 4);
        sq[rl][kq * 4 + 0] = v.x * v.x;
        sq[rl][kq * 4 + 1] = v.y * v.y;
        sq[rl][kq * 4 + 2] = v.z * v.z;
        sq[rl][kq * 4 + 3] = v.w * v.w;
    }
    __syncthreads();
    const int rl = tid >> 4, lane16 = tid & 15;
    float s = pairwise16(&sq[rl][0], lane16);
    if (lane16 == 0) enorm[row0 + rl] = s;
}

// ---------------------------------------------------------------- C_r emulation
// row r = b*1024 + hw; element k: z[b, k, hw]
__global__ void cnorm_kernel(const float* __restrict__ z, float* __restrict__ cnorm) {
    __shared__ float sq[16][257];
    const int tid = threadIdx.x;          // 256
    const int r0  = blockIdx.x * 16;      // 1024 blocks
    const int b   = r0 >> 10;
    const int hw0 = r0 & 1023;
    const float* zb = z + ((size_t)b << 18) + hw0;
#pragma unroll
    for (int p = 0; p < 4; p++) {
        int q = p * 256 + tid;            // 1024 quads: 256 channels x 4 hw-quads
        int c = q >> 2, hq = q & 3;
        float4 v = *(const float4*)(zb + ((size_t)c << 10) + hq * 4);
        sq[hq * 4 + 0][c] = v.x * v.x;
        sq[hq * 4 + 1][c] = v.y * v.y;
        sq[hq * 4 + 2][c] = v.z * v.z;
        sq[hq * 4 + 3][c] = v.w * v.w;
    }
    __syncthreads();
    const int rl = tid >> 4, lane16 = tid & 15;
    float s = pairwise16(&sq[rl][0], lane16);
    if (lane16 == 0) cnorm[r0 + rl] = s;
}

// ---------------------------------------------------------------- main top-2
// Score exactly as np fp32: D = fl( fl(C_r + E_j) - fl(2*G) ); ties -> lower j.
__launch_bounds__(512, 2)
__global__ void top2_kernel(const float* __restrict__ z, const float* __restrict__ emb,
                            const float* __restrict__ enorm, const float* __restrict__ cnorm,
                            float* __restrict__ out,
                            int* __restrict__ ws_i0, int* __restrict__ ws_hist,
                            float* __restrict__ ws_t0sum) {
    __shared__ float zs[64][68];    // [row(hw)][k]
    __shared__ float es[128][68];   // [code][k]

    const int tid = threadIdx.x;
    const int tx  = tid & 31;       // code lane (32)
    const int ty  = tid >> 5;       // row group (16)
    const int r0  = blockIdx.x * 64;
    const int b   = r0 >> 10;
    const int hw0 = r0 & 1023;
    const float* zbase = z + ((size_t)b << 18) + hw0;

    float C[4];
#pragma unroll
    for (int rr = 0; rr < 4; rr++) C[rr] = cnorm[r0 + ty + 16 * rr];

    float t0[4], t1[4];
    int   i0a[4], i1a[4];
#pragma unroll
    for (int rr = 0; rr < 4; rr++) {
        t0[rr] = FLT_MAX; t1[rr] = FLT_MAX;
        i0a[rr] = 0x7fffffff; i1a[rr] = 0x7fffffff;
    }

    for (int jt = 0; jt < 64; jt++) {
        float en[4];
#pragma unroll
        for (int cc = 0; cc < 4; cc++) en[cc] = enorm[jt * 128 + cc * 32 + tx];

        float acc[4][4];
#pragma unroll
        for (int rr = 0; rr < 4; rr++)
#pragma unroll
            for (int cc = 0; cc < 4; cc++) acc[rr][cc] = 0.f;

        for (int kc = 0; kc < 4; kc++) {
            __syncthreads();
#pragma unroll
            for (int p = 0; p < 4; p++) {
                int q = p * 512 + tid;
                int code = q >> 4, kq = q & 15;
                float4 v = *(const float4*)(emb + (size_t)(jt * 128 + code) * KD + kc * 64 + kq * 4);
                *(float4*)&es[code][kq * 4] = v;
            }
#pragma unroll
            for (int p = 0; p < 2; p++) {
                int q  = p * 512 + tid;
                int cl = q >> 4, hq = q & 15;
                float4 v = *(const float4*)(zbase + ((size_t)(kc * 64 + cl) << 10) + hq * 4);
                zs[hq * 4 + 0][cl] = v.x;
                zs[hq * 4 + 1][cl] = v.y;
                zs[hq * 4 + 2][cl] = v.z;
                zs[hq * 4 + 3][cl] = v.w;
            }
            __syncthreads();
#pragma unroll 4
            for (int ks = 0; ks < 16; ks++) {
                int k = ks * 4;
                float4 zf[4], ef[4];
#pragma unroll
                for (int rr = 0; rr < 4; rr++) zf[rr] = *(const float4*)&zs[ty + 16 * rr][k];
#pragma unroll
                for (int cc = 0; cc < 4; cc++) ef[cc] = *(const float4*)&es[tx + 32 * cc][k];
#pragma unroll
                for (int rr = 0; rr < 4; rr++)
#pragma unroll
                    for (int cc = 0; cc < 4; cc++)
                        acc[rr][cc] += zf[rr].x * ef[cc].x + zf[rr].y * ef[cc].y +
                                       zf[rr].z * ef[cc].z + zf[rr].w * ef[cc].w;
            }
        }
        // fold with fp32-quantized reference semantics
#pragma unroll
        for (int cc = 0; cc < 4; cc++) {
            int j = jt * 128 + cc * 32 + tx;
#pragma unroll
            for (int rr = 0; rr < 4; rr++) {
                float S = C[rr] + en[cc];            // fl(C + E): the big-term quantizer
                float t = S - 2.0f * acc[rr][cc];    // == fl(S - fl(2G)) since 2*acc exact
                if (t < t0[rr]) {
                    t1[rr] = t0[rr]; i1a[rr] = i0a[rr];
                    t0[rr] = t;      i0a[rr] = j;
                } else if (t < t1[rr]) {
                    t1[rr] = t; i1a[rr] = j;
                }
            }
        }
    }

    // butterfly merge across the 32 code lanes (tie-break: lower index wins)
#pragma unroll
    for (int m = 1; m < 32; m <<= 1) {
#pragma unroll
        for (int rr = 0; rr < 4; rr++) {
            float b0 = __shfl_xor(t0[rr], m);
            int  bi0 = __shfl_xor(i0a[rr], m);
            float b1 = __shfl_xor(t1[rr], m);
            int  bi1 = __shfl_xor(i1a[rr], m);
            if (b0 < t0[rr] || (b0 == t0[rr] && bi0 < i0a[rr])) {
                if (t0[rr] < b1 || (t0[rr] == b1 && i0a[rr] < bi1)) {
                    t1[rr] = t0[rr]; i1a[rr] = i0a[rr];
                } else {
                    t1[rr] = b1; i1a[rr] = bi1;
                }
                t0[rr] = b0; i0a[rr] = bi0;
            } else {
                if (b0 < t1[rr] || (b0 == t1[rr] && bi0 < i1a[rr])) {
                    t1[rr] = b0; i1a[rr] = bi0;
                }
            }
        }
    }

    if (tx == 0) {
        float tsum = 0.f;
#pragma unroll
        for (int rr = 0; rr < 4; rr++) {
            int r = r0 + ty + 16 * rr;
            out[OFF_I0 + r] = (float)i0a[rr];
            out[OFF_I1 + r] = (float)i1a[rr];
            ws_i0[r] = i0a[rr];
            out[OFF_ONEHOT + (size_t)r * NE + i0a[rr]] = 1.0f;
            atomicAdd(&ws_hist[i0a[rr]], 1);
            tsum += t0[rr];   // D = ||z-e||^2 (quantized): loss uses it directly
        }
        atomicAdd(ws_t0sum, tsum);
    }
}

// ---------------------------------------------------------------- z_q gather
__global__ void zq_kernel(const float* __restrict__ emb, const int* __restrict__ ws_i0,
                          float* __restrict__ out) {
    int bc = blockIdx.x;              // 4096 = 16 b * 256 c
    int bb = bc >> 8, c = bc & 255;
    int hwb = threadIdx.x * 4;        // 256 threads x 4 hw
    const int4 iv = *(const int4*)(ws_i0 + bb * 1024 + hwb);
    float* op = out + OFF_ZQ + ((size_t)bc << 10) + hwb;
    op[0] = emb[(size_t)iv.x * KD + c];
    op[1] = emb[(size_t)iv.y * KD + c];
    op[2] = emb[(size_t)iv.z * KD + c];
    op[3] = emb[(size_t)iv.w * KD + c];
}

// ---------------------------------------------------------------- finalize
__global__ void finalize_kernel(const int* __restrict__ hist, const float* __restrict__ t0sum,
                                float* __restrict__ out) {
    __shared__ float red[256];
    float s = 0.f;
    for (int j = threadIdx.x; j < NE; j += 256) {
        float p = (float)hist[j] * (1.0f / 16384.0f);
        s += p * logf(p + 1e-10f);
    }
    red[threadIdx.x] = s;
    __syncthreads();
    for (int m = 128; m; m >>= 1) {
        if (threadIdx.x < m) red[threadIdx.x] += red[threadIdx.x + m];
        __syncthreads();
    }
    if (threadIdx.x == 0) {
        out[OFF_PERP] = expf(-red[0]);
        // loss = 1.25 * mean((zq - zp)^2); sum over rows of D (= ||z-e||^2)
        out[OFF_LOSS] = 1.25f * t0sum[0] * (1.0f / 4194304.0f);
    }
}

extern "C" void kernel_launch(void* const* d_in, const int* in_sizes, int n_in,
                              void* d_out, int out_size, void* d_ws, size_t ws_size,
                              hipStream_t stream) {
    const float* z   = (const float*)d_in[0];
    const float* emb = (const float*)d_in[1];
    float* out = (float*)d_out;
    float* ws  = (float*)d_ws;

    int*   ws_i0    = (int*)ws + WS_I0;
    int*   ws_hist  = (int*)ws + WS_HIST;
    float* ws_enorm = ws + WS_ENORM;
    float* ws_cnorm = ws + WS_CNORM;
    float* ws_t0sum = ws + WS_T0SUM;

    hipLaunchKernelGGL(zero_ws_kernel, dim3(193), dim3(256), 0, stream, ws);
    hipLaunchKernelGGL(zero_onehot_kernel, dim3(4096), dim3(1024), 0, stream, out);
    hipLaunchKernelGGL(enorm_kernel, dim3(512), dim3(256), 0, stream, emb, ws_enorm);
    hipLaunchKernelGGL(cnorm_kernel, dim3(1024), dim3(256), 0, stream, z, ws_cnorm);
    hipLaunchKernelGGL(top2_kernel, dim3(256), dim3(512), 0, stream,
                       z, emb, ws_enorm, ws_cnorm, out, ws_i0, ws_hist, ws_t0sum);
    hipLaunchKernelGGL(zq_kernel, dim3(4096), dim3(256), 0, stream, emb, ws_i0, out);
    hipLaunchKernelGGL(finalize_kernel, dim3(1), dim3(256), 0, stream,
                       ws_hist, ws_t0sum, out);
}

// Round 5
// 1441.966 us; speedup vs baseline: 1.4476x; 1.4476x over previous
//
#include <hip/hip_runtime.h>
#include <cfloat>
#include <cstdint>
#include <cstddef>

// Problem constants
#define M_ROWS 16384
#define NE     8192
#define KD     256

// d_out layout (float elements)
#define OFF_LOSS   0ULL
#define OFF_ZQ     1ULL
#define OFF_PERP   4194305ULL
#define OFF_ONEHOT 4194306ULL
#define OFF_I0     138412034ULL
#define OFF_I1     138428418ULL

// Scratch inside the one-hot output region (zeroed AFTER use).
// base = out + OFF_ONEHOT + 2 (16B-aligned). Offsets in floats:
#define SCR_ZHI  0ULL        // bf16[16384][256] = 2,097,152 floats
#define SCR_ZLO  2097152ULL
#define SCR_EHI  4194304ULL  // bf16[8192][256] = 1,048,576 floats
#define SCR_PART 5242880ULL  // float4[16384][8][2] = 1,048,576 floats

// d_ws layout (4-byte units)
#define WS_I0    0        // int[16384]
#define WS_HIST  16384    // int[8192]
#define WS_ENORM 24576    // float[8192]
#define WS_CNORM 32768    // float[16384]
#define WS_T0SUM 49152    // double (2 slots, 8B-aligned)
#define WS_TOTAL 49154

typedef __bf16 bf16x8 __attribute__((ext_vector_type(8)));
typedef float  floatx16 __attribute__((ext_vector_type(16)));

__device__ __forceinline__ void async_load16(const void* g, void* lds) {
    __builtin_amdgcn_global_load_lds(
        (const __attribute__((address_space(1))) void*)g,
        (__attribute__((address_space(3))) void*)lds, 16, 0, 0);
}

// ---------------------------------------------------------------- zero ws
__global__ void zero_ws_kernel(float* __restrict__ ws) {
    int i = blockIdx.x * 256 + threadIdx.x;
    if (i < WS_TOTAL) ws[i] = 0.0f;
}

// ------------------------------------------------- zero one-hot region (537 MB)
__global__ void zero_onehot_kernel(float* __restrict__ out) {
    size_t tidg = (size_t)blockIdx.x * 1024 + threadIdx.x;   // 4096 x 1024
    float4* base = (float4*)(out + OFF_ONEHOT + 2);
    const float4 zz = make_float4(0.f, 0.f, 0.f, 0.f);
#pragma unroll
    for (int i = 0; i < 8; i++) {
        size_t q = tidg + (size_t)i * 4194304ULL;
        if (q < 33554431ULL) base[q] = zz;
    }
    if (tidg == 0) {
        out[OFF_ONEHOT + 0] = 0.f;
        out[OFF_ONEHOT + 1] = 0.f;
        out[OFF_ONEHOT + 134217726ULL] = 0.f;
        out[OFF_ONEHOT + 134217727ULL] = 0.f;
    }
}

// ---------------------------------------------------------------- scatter ones
__global__ void scatter_ones_kernel(const int* __restrict__ ws_i0, float* __restrict__ out) {
    int r = blockIdx.x * 256 + threadIdx.x;   // 64 x 256
    int j = ws_i0[r] & (NE - 1);              // defensive clamp
    out[OFF_ONEHOT + (size_t)r * NE + j] = 1.0f;
}

// ------------------------------------------------------------------------
// numpy float32 pairwise sum over 256 elements, emulated exactly (validated R2)
__device__ __forceinline__ float pairwise16(const float* sq, int lane16) {
    const int h = lane16 >> 3;
    const int j = lane16 & 7;
    float r = sq[h * 128 + j];
#pragma unroll
    for (int i = 1; i < 16; i++) r = r + sq[h * 128 + i * 8 + j];
    float s = r + __shfl_xor(r, 1);
    s = s + __shfl_xor(s, 2);
    s = s + __shfl_xor(s, 4);
    s = s + __shfl_xor(s, 8);
    return s;
}

// ---------------------------------------------------------------- E_j emulation
__global__ void enorm_kernel(const float* __restrict__ emb, float* __restrict__ enorm) {
    __shared__ float sq[16][257];
    const int tid = threadIdx.x;
    const int row0 = blockIdx.x * 16;
#pragma unroll
    for (int p = 0; p < 4; p++) {
        int q = p * 256 + tid;
        int rl = q >> 6, kq = q & 63;
        float4 v = *(const float4*)(emb + (size_t)(row0 + rl) * KD + kq * 4);
        sq[rl][kq * 4 + 0] = v.x * v.x;
        sq[rl][kq * 4 + 1] = v.y * v.y;
        sq[rl][kq * 4 + 2] = v.z * v.z;
        sq[rl][kq * 4 + 3] = v.w * v.w;
    }
    __syncthreads();
    const int rl = tid >> 4, lane16 = tid & 15;
    float s = pairwise16(&sq[rl][0], lane16);
    if (lane16 == 0) enorm[row0 + rl] = s;
}

// ---------------------------------------------------------------- C_r emulation
__global__ void cnorm_kernel(const float* __restrict__ z, float* __restrict__ cnorm) {
    __shared__ float sq[16][257];
    const int tid = threadIdx.x;
    const int r0  = blockIdx.x * 16;
    const int b   = r0 >> 10;
    const int hw0 = r0 & 1023;
    const float* zb = z + ((size_t)b << 18) + hw0;
#pragma unroll
    for (int p = 0; p < 4; p++) {
        int q = p * 256 + tid;
        int c = q >> 2, hq = q & 3;
        float4 v = *(const float4*)(zb + ((size_t)c << 10) + hq * 4);
        sq[hq * 4 + 0][c] = v.x * v.x;
        sq[hq * 4 + 1][c] = v.y * v.y;
        sq[hq * 4 + 2][c] = v.z * v.z;
        sq[hq * 4 + 3][c] = v.w * v.w;
    }
    __syncthreads();
    const int rl = tid >> 4, lane16 = tid & 15;
    float s = pairwise16(&sq[rl][0], lane16);
    if (lane16 == 0) cnorm[r0 + rl] = s;
}

// ---------------------------------------------------------------- z hi/lo split (+transpose)
__global__ void split_z_kernel(const float* __restrict__ z,
                               __bf16* __restrict__ zhi, __bf16* __restrict__ zlo) {
    __shared__ float tile[64][65];
    const int tid = threadIdx.x;            // 256
    const int r0  = blockIdx.x * 64;        // 256 row-blocks
    const int kb  = blockIdx.y;             // 4 k-blocks of 64
    const int b   = r0 >> 10;
    const int hw0 = r0 & 1023;
#pragma unroll
    for (int p = 0; p < 4; p++) {
        int q = p * 256 + tid;
        int cl = q >> 4, hq = q & 15;
        float4 v = *(const float4*)(z + ((size_t)b << 18) + (size_t)(kb * 64 + cl) * 1024 + hw0 + hq * 4);
        tile[hq * 4 + 0][cl] = v.x;
        tile[hq * 4 + 1][cl] = v.y;
        tile[hq * 4 + 2][cl] = v.z;
        tile[hq * 4 + 3][cl] = v.w;
    }
    __syncthreads();
#pragma unroll
    for (int p = 0; p < 2; p++) {
        int u = p * 256 + tid;
        int row = u >> 3, k8 = u & 7;
        bf16x8 vh, vl;
#pragma unroll
        for (int e = 0; e < 8; e++) {
            float x = tile[row][k8 * 8 + e];
            __bf16 h = (__bf16)x;
            vh[e] = h;
            vl[e] = (__bf16)(x - (float)h);
        }
        size_t go = ((size_t)(r0 + row) << 8) + kb * 64 + k8 * 8;
        *(bf16x8*)(zhi + go) = vh;
        *(bf16x8*)(zlo + go) = vl;
    }
}

// ---------------------------------------------------------------- e hi split
__global__ void split_e_kernel(const float* __restrict__ emb, __bf16* __restrict__ ehi) {
    int u = blockIdx.x * 256 + threadIdx.x;   // 1024 x 256 = 262144 octets
    size_t go = (size_t)u * 8;
    float4 v0 = *(const float4*)(emb + go);
    float4 v1 = *(const float4*)(emb + go + 4);
    float x[8] = {v0.x, v0.y, v0.z, v0.w, v1.x, v1.y, v1.z, v1.w};
    bf16x8 vh;
#pragma unroll
    for (int e = 0; e < 8; e++) vh[e] = (__bf16)x[e];
    *(bf16x8*)(ehi + go) = vh;
}

// ---------------------------------------------------------------- helpers
// LDS tile: 128 rows x 64 k bf16, 16B units, XOR swizzle (m, ku)->slot m*8+(ku^(m&7))
__device__ __forceinline__ void stage_tile(__bf16* lds, const __bf16* g, int row0, int kc,
                                           int wid, int lane) {
#pragma unroll
    for (int p = 0; p < 4; p++) {
        int sb = wid * 256 + p * 64;
        int s  = sb + lane;
        int m  = s >> 3, kj = s & 7;
        int ku = kj ^ (m & 7);
        const __bf16* gp = g + (((size_t)(row0 + m)) << 8) + kc * 64 + ku * 8;
        async_load16((const void*)gp, (void*)(lds + sb * 8));
    }
}

__device__ __forceinline__ bf16x8 frag_ld(const __bf16* lds, int rc, int ku) {
    int slot = rc * 8 + (ku ^ (rc & 7));
    return *(const bf16x8*)(lds + slot * 8);
}

#define MFMA(d, a, b) d = __builtin_amdgcn_mfma_f32_32x32x16_bf16(a, b, d, 0, 0, 0)

__device__ __forceinline__ bool lex_lt(float t, int i, float T, int I) {
    return (t < T) || (t == T && i < I);
}

// insert (t,i) into sorted top-4 (t0<=t1<=t2<=t3, lex tie by index)
__device__ __forceinline__ void ins4(float t, int i,
    float& t0, int& i0, float& t1, int& i1,
    float& t2, int& i2, float& t3, int& i3) {
    if (lex_lt(t, i, t3, i3)) {
        if (lex_lt(t, i, t2, i2)) {
            t3 = t2; i3 = i2;
            if (lex_lt(t, i, t1, i1)) {
                t2 = t1; i2 = i1;
                if (lex_lt(t, i, t0, i0)) { t1 = t0; i1 = i0; t0 = t; i0 = i; }
                else { t1 = t; i1 = i; }
            } else { t2 = t; i2 = i; }
        } else { t3 = t; i3 = i; }
    }
}

// ---------------------------------------------------------------- MFMA top-4 filter
__launch_bounds__(256, 2)
__global__ void mfma_top4_kernel(const __bf16* __restrict__ ehi,
                                 const __bf16* __restrict__ zhi, const __bf16* __restrict__ zlo,
                                 const float* __restrict__ enorm_g, const float* __restrict__ cnorm_g,
                                 float4* __restrict__ part) {
    __shared__ __bf16 Ahi[128 * 64], Bhi[128 * 64], Blo[128 * 64];
    __shared__ float en_lds[128];
    __shared__ float mbuf[128][8];

    const int tid = threadIdx.x;
    const int lane = tid & 63, wid = tid >> 6;
    const int l31 = lane & 31, half = lane >> 5;
    const int wave_m = wid & 1, wave_n = wid >> 1;
    const int zb = blockIdx.x, jg = blockIdx.y;
    const int brow0 = zb * 128;

    const int rcA0 = wave_m * 64 + l31, rcA1 = rcA0 + 32;
    const int rcB0 = wave_n * 64 + l31, rcB1 = rcB0 + 32;

    float Cn[2];
    Cn[0] = cnorm_g[brow0 + wave_n * 64 + l31];
    Cn[1] = cnorm_g[brow0 + wave_n * 64 + 32 + l31];

    float q0[2], q1[2], q2[2], q3[2];
    int   j0[2], j1[2], j2[2], j3[2];
#pragma unroll
    for (int s = 0; s < 2; s++) {
        q0[s] = q1[s] = q2[s] = q3[s] = FLT_MAX;
        j0[s] = j1[s] = j2[s] = j3[s] = 0x7fffffff;
    }

    for (int jt = 0; jt < 8; jt++) {
        const int jbase = jg * 1024 + jt * 128;
        floatx16 acc00 = (floatx16)0.f, acc01 = (floatx16)0.f,
                 acc10 = (floatx16)0.f, acc11 = (floatx16)0.f;
        for (int kc = 0; kc < 4; kc++) {
            __syncthreads();
            if (kc == 0 && tid < 128) en_lds[tid] = enorm_g[jbase + tid];
            stage_tile(Ahi, ehi, jbase, kc, wid, lane);
            stage_tile(Bhi, zhi, brow0, kc, wid, lane);
            stage_tile(Blo, zlo, brow0, kc, wid, lane);
            __syncthreads();
#pragma unroll
            for (int ks = 0; ks < 4; ks++) {
                const int ku = ks * 2 + half;
                bf16x8 a0 = frag_ld(Ahi, rcA0, ku);
                bf16x8 a1 = frag_ld(Ahi, rcA1, ku);
                bf16x8 h0 = frag_ld(Bhi, rcB0, ku);
                bf16x8 h1 = frag_ld(Bhi, rcB1, ku);
                bf16x8 l0 = frag_ld(Blo, rcB0, ku);
                bf16x8 l1 = frag_ld(Blo, rcB1, ku);
                MFMA(acc00, a0, h0); MFMA(acc00, a0, l0);
                MFMA(acc01, a0, h1); MFMA(acc01, a0, l1);
                MFMA(acc10, a1, h0); MFMA(acc10, a1, l0);
                MFMA(acc11, a1, h1); MFMA(acc11, a1, l1);
            }
        }
        // fold: C/D layout 32x32: col = lane&31 (zrow), row = (reg&3)+8*(reg>>2)+4*half (code)
#pragma unroll
        for (int a = 0; a < 2; a++) {
#pragma unroll
            for (int reg = 0; reg < 16; reg++) {
                const int rl = (reg & 3) + 8 * (reg >> 2) + 4 * half;
                const int cl = wave_m * 64 + a * 32 + rl;
                const int code = jbase + cl;
                const float E = en_lds[cl];
                float g0 = (a == 0) ? acc00[reg] : acc10[reg];
                float g1 = (a == 0) ? acc01[reg] : acc11[reg];
                float ta = fmaf(-2.0f, g0, Cn[0] + E);
                ins4(ta, code, q0[0], j0[0], q1[0], j1[0], q2[0], j2[0], q3[0], j3[0]);
                float tb = fmaf(-2.0f, g1, Cn[1] + E);
                ins4(tb, code, q0[1], j0[1], q1[1], j1[1], q2[1], j2[1], q3[1], j3[1]);
            }
        }
    }

    // lane <-> lane+32 merge (same zrow, complementary code sets)
#pragma unroll
    for (int s = 0; s < 2; s++) {
        float ot0 = __shfl_xor(q0[s], 32), ot1 = __shfl_xor(q1[s], 32),
              ot2 = __shfl_xor(q2[s], 32), ot3 = __shfl_xor(q3[s], 32);
        int oi0 = __shfl_xor(j0[s], 32), oi1 = __shfl_xor(j1[s], 32),
            oi2 = __shfl_xor(j2[s], 32), oi3 = __shfl_xor(j3[s], 32);
        ins4(ot0, oi0, q0[s], j0[s], q1[s], j1[s], q2[s], j2[s], q3[s], j3[s]);
        ins4(ot1, oi1, q0[s], j0[s], q1[s], j1[s], q2[s], j2[s], q3[s], j3[s]);
        ins4(ot2, oi2, q0[s], j0[s], q1[s], j1[s], q2[s], j2[s], q3[s], j3[s]);
        ins4(ot3, oi3, q0[s], j0[s], q1[s], j1[s], q2[s], j2[s], q3[s], j3[s]);
    }

    __syncthreads();
    if (wave_m == 1 && lane < 32) {
#pragma unroll
        for (int s = 0; s < 2; s++) {
            int zr = wave_n * 64 + s * 32 + l31;
            mbuf[zr][0] = q0[s]; mbuf[zr][1] = q1[s]; mbuf[zr][2] = q2[s]; mbuf[zr][3] = q3[s];
            mbuf[zr][4] = __int_as_float(j0[s]); mbuf[zr][5] = __int_as_float(j1[s]);
            mbuf[zr][6] = __int_as_float(j2[s]); mbuf[zr][7] = __int_as_float(j3[s]);
        }
    }
    __syncthreads();
    if (wave_m == 0 && lane < 32) {
#pragma unroll
        for (int s = 0; s < 2; s++) {
            int zr = wave_n * 64 + s * 32 + l31;
            ins4(mbuf[zr][0], __float_as_int(mbuf[zr][4]),
                 q0[s], j0[s], q1[s], j1[s], q2[s], j2[s], q3[s], j3[s]);
            ins4(mbuf[zr][1], __float_as_int(mbuf[zr][5]),
                 q0[s], j0[s], q1[s], j1[s], q2[s], j2[s], q3[s], j3[s]);
            ins4(mbuf[zr][2], __float_as_int(mbuf[zr][6]),
                 q0[s], j0[s], q1[s], j1[s], q2[s], j2[s], q3[s], j3[s]);
            ins4(mbuf[zr][3], __float_as_int(mbuf[zr][7]),
                 q0[s], j0[s], q1[s], j1[s], q2[s], j2[s], q3[s], j3[s]);
            float4 pa = make_float4(q0[s], q1[s], q2[s], q3[s]);
            float4 pb = make_float4(__int_as_float(j0[s]), __int_as_float(j1[s]),
                                    __int_as_float(j2[s]), __int_as_float(j3[s]));
            size_t base = ((size_t)(brow0 + zr) * 8 + jg) * 2;
            part[base] = pa;
            part[base + 1] = pb;
        }
    }
}

// ---------------------------------------------------------------- fp64 rescore, wave-per-row
// Shortlist = candidates with raw t~ <= m2 + 1.2e-4. Exact: t = fl32(fl32(C+E)-fl32(2*G64)).
__global__ void rescore_kernel(const float* __restrict__ z, const float* __restrict__ emb,
                               const float* __restrict__ enorm_g, const float* __restrict__ cnorm_g,
                               const float4* __restrict__ part, float* __restrict__ out,
                               int* __restrict__ ws_i0, int* __restrict__ hist,
                               double* __restrict__ t0sum) {
    const int tid  = threadIdx.x;
    const int lane = tid & 63, wid = tid >> 6;
    const int r = blockIdx.x * 4 + wid;       // 4096 blocks x 4 waves
    const int b = r >> 10, hw = r & 1023;
    const float* zb = z + ((size_t)b << 18) + hw;

    // this lane's 4 channels of the row, in fp64
    const int c4 = lane * 4;
    const double zv0 = (double)zb[(size_t)(c4 + 0) << 10];
    const double zv1 = (double)zb[(size_t)(c4 + 1) << 10];
    const double zv2 = (double)zb[(size_t)(c4 + 2) << 10];
    const double zv3 = (double)zb[(size_t)(c4 + 3) << 10];

    // pass A: m1, m2 over raw t~ (uniform reads; redundant per lane)
    float m1 = FLT_MAX, m2 = FLT_MAX;
    for (int jg = 0; jg < 8; jg++) {
        float4 pa = part[((size_t)r * 8 + jg) * 2];
        if (pa.x < m1) { m2 = m1; m1 = pa.x; } else if (pa.x < m2) m2 = pa.x;
        if (pa.y < m1) { m2 = m1; m1 = pa.y; } else if (pa.y < m2) m2 = pa.y;
    }
    const float T = m2 + 1.2e-4f;
    const float C = cnorm_g[r];

    float bt0 = FLT_MAX, bt1 = FLT_MAX;
    int   bi0 = NE - 1, bi1 = NE - 1;
    bool  any = false;
    for (int jg = 0; jg < 8; jg++) {
        float4 pa = part[((size_t)r * 8 + jg) * 2];
        float4 pb = part[((size_t)r * 8 + jg) * 2 + 1];
        float tv[4] = {pa.x, pa.y, pa.z, pa.w};
        int   jv[4] = {__float_as_int(pb.x), __float_as_int(pb.y),
                       __float_as_int(pb.z), __float_as_int(pb.w)};
        for (int e = 0; e < 4; e++) {
            if (tv[e] <= T) {            // uniform across wave
                const int j = jv[e] & (NE - 1);   // defensive clamp
                const float* er = emb + ((size_t)j << 8);
                float4 ev = *(const float4*)(er + c4);
                double gl = zv0 * (double)ev.x + zv1 * (double)ev.y +
                            zv2 * (double)ev.z + zv3 * (double)ev.w;
#pragma unroll
                for (int m = 1; m < 64; m <<= 1) gl += __shfl_xor(gl, m);
                float g2 = (float)(2.0 * gl);
                float S = C + enorm_g[j];
                float tex = S - g2;
                if (tex < bt0 || (tex == bt0 && j < bi0)) {
                    bt1 = bt0; bi1 = bi0; bt0 = tex; bi0 = j;
                } else if (tex < bt1 || (tex == bt1 && j < bi1)) {
                    bt1 = tex; bi1 = j;
                }
                any = true;
            }
        }
    }
    if (!any) { bt0 = 0.f; bi0 = 0; bi1 = 0; }   // unreachable; keeps writes sane

    if (lane == 0) {
        out[OFF_I0 + r] = (float)bi0;
        out[OFF_I1 + r] = (float)bi1;
        ws_i0[r] = bi0;
        atomicAdd(&hist[bi0], 1);
    }
    __shared__ double red[4];
    if (lane == 0) red[wid] = (double)bt0;
    __syncthreads();
    if (tid == 0) atomicAdd(t0sum, (red[0] + red[1]) + (red[2] + red[3]));
}

// ---------------------------------------------------------------- z_q gather
__global__ void zq_kernel(const float* __restrict__ emb, const int* __restrict__ ws_i0,
                          float* __restrict__ out) {
    int bc = blockIdx.x;              // 4096 = 16 b * 256 c
    int bb = bc >> 8, c = bc & 255;
    int hwb = threadIdx.x * 4;
    const int4 iv = *(const int4*)(ws_i0 + bb * 1024 + hwb);
    float* op = out + OFF_ZQ + ((size_t)bc << 10) + hwb;
    op[0] = emb[(size_t)(iv.x & (NE - 1)) * KD + c];
    op[1] = emb[(size_t)(iv.y & (NE - 1)) * KD + c];
    op[2] = emb[(size_t)(iv.z & (NE - 1)) * KD + c];
    op[3] = emb[(size_t)(iv.w & (NE - 1)) * KD + c];
}

// ---------------------------------------------------------------- finalize
__global__ void finalize_kernel(const int* __restrict__ hist, const double* __restrict__ t0sum,
                                float* __restrict__ out) {
    __shared__ float red[256];
    float s = 0.f;
    for (int j = threadIdx.x; j < NE; j += 256) {
        float p = (float)hist[j] * (1.0f / 16384.0f);
        s += p * logf(p + 1e-10f);
    }
    red[threadIdx.x] = s;
    __syncthreads();
    for (int m = 128; m; m >>= 1) {
        if (threadIdx.x < m) red[threadIdx.x] += red[threadIdx.x + m];
        __syncthreads();
    }
    if (threadIdx.x == 0) {
        out[OFF_PERP] = expf(-red[0]);
        out[OFF_LOSS] = 1.25f * (float)(t0sum[0] * (1.0 / 4194304.0));
    }
}

extern "C" void kernel_launch(void* const* d_in, const int* in_sizes, int n_in,
                              void* d_out, int out_size, void* d_ws, size_t ws_size,
                              hipStream_t stream) {
    const float* z   = (const float*)d_in[0];
    const float* emb = (const float*)d_in[1];
    float* out = (float*)d_out;
    float* ws  = (float*)d_ws;

    int*    ws_i0    = (int*)ws + WS_I0;
    int*    ws_hist  = (int*)ws + WS_HIST;
    float*  ws_enorm = ws + WS_ENORM;
    float*  ws_cnorm = ws + WS_CNORM;
    double* ws_t0sum = (double*)(ws + WS_T0SUM);

    float* scr = out + OFF_ONEHOT + 2;   // 16B-aligned scratch in one-hot region
    __bf16* zhi = (__bf16*)(scr + SCR_ZHI);
    __bf16* zlo = (__bf16*)(scr + SCR_ZLO);
    __bf16* ehi = (__bf16*)(scr + SCR_EHI);
    float4* part = (float4*)(scr + SCR_PART);

    hipLaunchKernelGGL(zero_ws_kernel, dim3(193), dim3(256), 0, stream, ws);
    hipLaunchKernelGGL(enorm_kernel, dim3(512), dim3(256), 0, stream, emb, ws_enorm);
    hipLaunchKernelGGL(cnorm_kernel, dim3(1024), dim3(256), 0, stream, z, ws_cnorm);
    hipLaunchKernelGGL(split_z_kernel, dim3(256, 4), dim3(256), 0, stream, z, zhi, zlo);
    hipLaunchKernelGGL(split_e_kernel, dim3(1024), dim3(256), 0, stream, emb, ehi);
    hipLaunchKernelGGL(mfma_top4_kernel, dim3(128, 8), dim3(256), 0, stream,
                       ehi, zhi, zlo, ws_enorm, ws_cnorm, part);
    hipLaunchKernelGGL(rescore_kernel, dim3(4096), dim3(256), 0, stream,
                       z, emb, ws_enorm, ws_cnorm, part, out, ws_i0, ws_hist, ws_t0sum);
    hipLaunchKernelGGL(zero_onehot_kernel, dim3(4096), dim3(1024), 0, stream, out);
    hipLaunchKernelGGL(scatter_ones_kernel, dim3(64), dim3(256), 0, stream, ws_i0, out);
    hipLaunchKernelGGL(zq_kernel, dim3(4096), dim3(256), 0, stream, emb, ws_i0, out);
    hipLaunchKernelGGL(finalize_kernel, dim3(1), dim3(256), 0, stream,
                       ws_hist, ws_t0sum, out);
}

// Round 6
// 1306.389 us; speedup vs baseline: 1.5978x; 1.1038x over previous
//
#include <hip/hip_runtime.h>
#include <cfloat>
#include <cstdint>
#include <cstddef>

// Problem constants
#define M_ROWS 16384
#define NE     8192
#define KD     256

// d_out layout (float elements)
#define OFF_LOSS   0ULL
#define OFF_ZQ     1ULL
#define OFF_PERP   4194305ULL
#define OFF_ONEHOT 4194306ULL
#define OFF_I0     138412034ULL
#define OFF_I1     138428418ULL

// Scratch inside the one-hot output region (zeroed AFTER use).
// base = out + OFF_ONEHOT + 2 (16B-aligned). Offsets in floats:
#define SCR_Z16  0ULL        // fp16[16384][256] swizzled = 2,097,152 floats
#define SCR_E16  2097152ULL  // fp16[8192][256] swizzled (x256 scale) = 1,048,576 floats
#define SCR_PART 3145728ULL  // float4[16384][8][2] = 1,048,576 floats

// d_ws layout (4-byte units)
#define WS_I0    0        // int[16384]
#define WS_HIST  16384    // int[8192]
#define WS_ENORM 24576    // float[8192]
#define WS_CNORM 32768    // float[16384]
#define WS_T0SUM 49152    // double (2 slots, 8B-aligned)
#define WS_TOTAL 49154

typedef _Float16 fp16x8 __attribute__((ext_vector_type(8)));
typedef float    floatx16 __attribute__((ext_vector_type(16)));

__device__ __forceinline__ void async_load16(const void* g, void* lds) {
    __builtin_amdgcn_global_load_lds(
        (const __attribute__((address_space(1))) void*)g,
        (__attribute__((address_space(3))) void*)lds, 16, 0, 0);
}

// ---------------------------------------------------------------- zero ws
__global__ void zero_ws_kernel(float* __restrict__ ws) {
    int i = blockIdx.x * 256 + threadIdx.x;
    if (i < WS_TOTAL) ws[i] = 0.0f;
}

// ------------------------------------------------- zero one-hot region (537 MB)
__global__ void zero_onehot_kernel(float* __restrict__ out) {
    size_t tidg = (size_t)blockIdx.x * 1024 + threadIdx.x;   // 4096 x 1024
    float4* base = (float4*)(out + OFF_ONEHOT + 2);
    const float4 zz = make_float4(0.f, 0.f, 0.f, 0.f);
#pragma unroll
    for (int i = 0; i < 8; i++) {
        size_t q = tidg + (size_t)i * 4194304ULL;
        if (q < 33554431ULL) base[q] = zz;
    }
    if (tidg == 0) {
        out[OFF_ONEHOT + 0] = 0.f;
        out[OFF_ONEHOT + 1] = 0.f;
        out[OFF_ONEHOT + 134217726ULL] = 0.f;
        out[OFF_ONEHOT + 134217727ULL] = 0.f;
    }
}

// ---------------------------------------------------------------- scatter ones
__global__ void scatter_ones_kernel(const int* __restrict__ ws_i0, float* __restrict__ out) {
    int r = blockIdx.x * 256 + threadIdx.x;   // 64 x 256
    int j = ws_i0[r] & (NE - 1);              // defensive clamp
    out[OFF_ONEHOT + (size_t)r * NE + j] = 1.0f;
}

// ------------------------------------------------------------------------
// numpy float32 pairwise sum over 256 elements, emulated exactly (validated R2)
__device__ __forceinline__ float pairwise16(const float* sq, int lane16) {
    const int h = lane16 >> 3;
    const int j = lane16 & 7;
    float r = sq[h * 128 + j];
#pragma unroll
    for (int i = 1; i < 16; i++) r = r + sq[h * 128 + i * 8 + j];
    float s = r + __shfl_xor(r, 1);
    s = s + __shfl_xor(s, 2);
    s = s + __shfl_xor(s, 4);
    s = s + __shfl_xor(s, 8);
    return s;
}

// ---------------------------------------------------------------- E_j emulation
__global__ void enorm_kernel(const float* __restrict__ emb, float* __restrict__ enorm) {
    __shared__ float sq[16][257];
    const int tid = threadIdx.x;
    const int row0 = blockIdx.x * 16;
#pragma unroll
    for (int p = 0; p < 4; p++) {
        int q = p * 256 + tid;
        int rl = q >> 6, kq = q & 63;
        float4 v = *(const float4*)(emb + (size_t)(row0 + rl) * KD + kq * 4);
        sq[rl][kq * 4 + 0] = v.x * v.x;
        sq[rl][kq * 4 + 1] = v.y * v.y;
        sq[rl][kq * 4 + 2] = v.z * v.z;
        sq[rl][kq * 4 + 3] = v.w * v.w;
    }
    __syncthreads();
    const int rl = tid >> 4, lane16 = tid & 15;
    float s = pairwise16(&sq[rl][0], lane16);
    if (lane16 == 0) enorm[row0 + rl] = s;
}

// ---------------------------------------------------------------- C_r emulation
__global__ void cnorm_kernel(const float* __restrict__ z, float* __restrict__ cnorm) {
    __shared__ float sq[16][257];
    const int tid = threadIdx.x;
    const int r0  = blockIdx.x * 16;
    const int b   = r0 >> 10;
    const int hw0 = r0 & 1023;
    const float* zb = z + ((size_t)b << 18) + hw0;
#pragma unroll
    for (int p = 0; p < 4; p++) {
        int q = p * 256 + tid;
        int c = q >> 2, hq = q & 3;
        float4 v = *(const float4*)(zb + ((size_t)c << 10) + hq * 4);
        sq[hq * 4 + 0][c] = v.x * v.x;
        sq[hq * 4 + 1][c] = v.y * v.y;
        sq[hq * 4 + 2][c] = v.z * v.z;
        sq[hq * 4 + 3][c] = v.w * v.w;
    }
    __syncthreads();
    const int rl = tid >> 4, lane16 = tid & 15;
    float s = pairwise16(&sq[rl][0], lane16);
    if (lane16 == 0) cnorm[r0 + rl] = s;
}

// ---------------------------------------------------------------- z -> fp16 (K-blocked swizzled)
// Global layout: 16B-unit index = ((row>>7)*4 + kc)*1024 + (row&127)*8 + (ku8 ^ (row&7))
// where k = kc*64 + ku8*8 + e. A 128-row x 64-k tile is a flat contiguous 16 KB chunk.
__global__ void split_z_kernel(const float* __restrict__ z, _Float16* __restrict__ z16) {
    __shared__ float tile[64][65];
    const int tid = threadIdx.x;            // 256
    const int r0  = blockIdx.x * 64;        // 256 row-blocks
    const int kb  = blockIdx.y;             // 4 k-blocks of 64
    const int b   = r0 >> 10;
    const int hw0 = r0 & 1023;
#pragma unroll
    for (int p = 0; p < 4; p++) {
        int q = p * 256 + tid;
        int cl = q >> 4, hq = q & 15;
        float4 v = *(const float4*)(z + ((size_t)b << 18) + (size_t)(kb * 64 + cl) * 1024 + hw0 + hq * 4);
        tile[hq * 4 + 0][cl] = v.x;
        tile[hq * 4 + 1][cl] = v.y;
        tile[hq * 4 + 2][cl] = v.z;
        tile[hq * 4 + 3][cl] = v.w;
    }
    __syncthreads();
#pragma unroll
    for (int p = 0; p < 2; p++) {
        int u = p * 256 + tid;              // 512 octets: 64 rows x 8 k8
        int row = u >> 3, k8 = u & 7;
        int r = r0 + row;
        fp16x8 vh;
#pragma unroll
        for (int e = 0; e < 8; e++) vh[e] = (_Float16)tile[row][k8 * 8 + e];
        size_t unit = ((size_t)(r >> 7) * 4 + kb) * 1024 + (size_t)(r & 127) * 8 + (k8 ^ (r & 7));
        *(fp16x8*)(z16 + unit * 8) = vh;
    }
}

// ---------------------------------------------------------------- e -> fp16*256 (same layout)
__global__ void split_e_kernel(const float* __restrict__ emb, _Float16* __restrict__ e16) {
    int u = blockIdx.x * 256 + threadIdx.x;   // 1024 x 256 = 262144 octets
    size_t go = (size_t)u * 8;                // = code*256 + kc*64 + ku8*8
    float4 v0 = *(const float4*)(emb + go);
    float4 v1 = *(const float4*)(emb + go + 4);
    float x[8] = {v0.x, v0.y, v0.z, v0.w, v1.x, v1.y, v1.z, v1.w};
    fp16x8 vh;
#pragma unroll
    for (int e = 0; e < 8; e++) vh[e] = (_Float16)(x[e] * 256.0f);  // exact pow2 scale, avoids subnormals
    int code = u >> 5, kc = (u >> 3) & 3, ku8 = u & 7;
    int kj = ku8 ^ (code & 7);
    size_t unit = ((size_t)(code >> 7) * 4 + kc) * 1024 + (size_t)(code & 127) * 8 + kj;
    *(fp16x8*)(e16 + unit * 8) = vh;
}

// ---------------------------------------------------------------- helpers
// Stage one contiguous 16 KB tile (1024 16B-units): each instruction = contiguous 1 KB.
__device__ __forceinline__ void stage16k(_Float16* lds, const _Float16* gsrc,
                                         int wid, int lane) {
#pragma unroll
    for (int p = 0; p < 4; p++) {
        int u = p * 256 + wid * 64;    // wave-uniform base unit
        async_load16((const void*)(gsrc + (size_t)(u + lane) * 8),
                     (void*)(lds + (size_t)u * 8));
    }
}

__device__ __forceinline__ fp16x8 frag_ld(const _Float16* lds, int rc, int ku) {
    int slot = rc * 8 + (ku ^ (rc & 7));
    return *(const fp16x8*)(lds + slot * 8);
}

#define MFMA(d, a, b) d = __builtin_amdgcn_mfma_f32_32x32x16_f16(a, b, d, 0, 0, 0)

__device__ __forceinline__ bool lex_lt(float t, int i, float T, int I) {
    return (t < T) || (t == T && i < I);
}

__device__ __forceinline__ void ins4(float t, int i,
    float& t0, int& i0, float& t1, int& i1,
    float& t2, int& i2, float& t3, int& i3) {
    if (lex_lt(t, i, t3, i3)) {
        if (lex_lt(t, i, t2, i2)) {
            t3 = t2; i3 = i2;
            if (lex_lt(t, i, t1, i1)) {
                t2 = t1; i2 = i1;
                if (lex_lt(t, i, t0, i0)) { t1 = t0; i1 = i0; t0 = t; i0 = i; }
                else { t1 = t; i1 = i; }
            } else { t2 = t; i2 = i; }
        } else { t3 = t; i3 = i; }
    }
}

// ---------------------------------------------------------------- MFMA top-4 filter (fp16)
// acc = sum z16 * (256*e16), t~ = fmaf(-2/256, acc, C+E). Noise sigma(2G) ~ 2.2e-6,
// covered by rescore slack 1.2e-4. Double-buffered contiguous staging, 2 blocks/CU.
__launch_bounds__(256, 2)
__global__ void mfma_top4_kernel(const _Float16* __restrict__ e16, const _Float16* __restrict__ z16,
                                 const float* __restrict__ enorm_g, const float* __restrict__ cnorm_g,
                                 float4* __restrict__ part) {
    __shared__ _Float16 As[2][8192];   // 2 x 16 KB
    __shared__ _Float16 Bs[2][8192];   // 2 x 16 KB
    __shared__ float en_all[1024];     // 4 KB
    __shared__ float mbuf[128][8];     // 4 KB

    const int tid = threadIdx.x;
    const int lane = tid & 63, wid = tid >> 6;
    const int l31 = lane & 31, half = lane >> 5;
    const int wave_m = wid & 1, wave_n = wid >> 1;
    const int zb = blockIdx.x, jg = blockIdx.y;
    const int brow0 = zb * 128;

    const int rcA0 = wave_m * 64 + l31, rcA1 = rcA0 + 32;
    const int rcB0 = wave_n * 64 + l31, rcB1 = rcB0 + 32;

    // preload all 1024 e-norms for this jg
#pragma unroll
    for (int p = 0; p < 4; p++) en_all[p * 256 + tid] = enorm_g[jg * 1024 + p * 256 + tid];

    float Cn[2];
    Cn[0] = cnorm_g[brow0 + wave_n * 64 + l31];
    Cn[1] = cnorm_g[brow0 + wave_n * 64 + 32 + l31];

    float q0[2], q1[2], q2[2], q3[2];
    int   j0[2], j1[2], j2[2], j3[2];
#pragma unroll
    for (int s = 0; s < 2; s++) {
        q0[s] = q1[s] = q2[s] = q3[s] = FLT_MAX;
        j0[s] = j1[s] = j2[s] = j3[s] = 0x7fffffff;
    }

    // prologue: stage iter 0 into buffer 0
    stage16k(As[0], e16 + ((size_t)((jg * 8 + 0) * 4 + 0) * 1024) * 8, wid, lane);
    stage16k(Bs[0], z16 + ((size_t)(zb * 4 + 0) * 1024) * 8, wid, lane);
    __syncthreads();

    floatx16 acc00, acc01, acc10, acc11;
    for (int iter = 0; iter < 32; iter++) {
        const int jt = iter >> 2, kc = iter & 3;
        const int cur = iter & 1;
        if (kc == 0) {
            acc00 = (floatx16)0.f; acc01 = (floatx16)0.f;
            acc10 = (floatx16)0.f; acc11 = (floatx16)0.f;
        }
        if (iter < 31) {   // issue next-tile loads (land by next barrier)
            const int ni = iter + 1, njt = ni >> 2, nkc = ni & 3;
            stage16k(As[cur ^ 1], e16 + ((size_t)((jg * 8 + njt) * 4 + nkc) * 1024) * 8, wid, lane);
            stage16k(Bs[cur ^ 1], z16 + ((size_t)(zb * 4 + nkc) * 1024) * 8, wid, lane);
        }
#pragma unroll
        for (int ks = 0; ks < 4; ks++) {
            const int ku = ks * 2 + half;
            fp16x8 a0 = frag_ld(As[cur], rcA0, ku);
            fp16x8 a1 = frag_ld(As[cur], rcA1, ku);
            fp16x8 b0 = frag_ld(Bs[cur], rcB0, ku);
            fp16x8 b1 = frag_ld(Bs[cur], rcB1, ku);
            MFMA(acc00, a0, b0);
            MFMA(acc01, a0, b1);
            MFMA(acc10, a1, b0);
            MFMA(acc11, a1, b1);
        }
        if (kc == 3) {
            const int jbase = jg * 1024 + jt * 128;
            // C/D layout 32x32: col = lane&31 (zrow), row = (reg&3)+8*(reg>>2)+4*half (code)
#pragma unroll
            for (int a = 0; a < 2; a++) {
#pragma unroll
                for (int reg = 0; reg < 16; reg++) {
                    const int rl = (reg & 3) + 8 * (reg >> 2) + 4 * half;
                    const int cl = wave_m * 64 + a * 32 + rl;
                    const int code = jbase + cl;
                    const float E = en_all[jt * 128 + cl];
                    float g0 = (a == 0) ? acc00[reg] : acc10[reg];
                    float g1 = (a == 0) ? acc01[reg] : acc11[reg];
                    float ta = fmaf(-0.0078125f, g0, Cn[0] + E);   // -2/256 * acc
                    ins4(ta, code, q0[0], j0[0], q1[0], j1[0], q2[0], j2[0], q3[0], j3[0]);
                    float tb = fmaf(-0.0078125f, g1, Cn[1] + E);
                    ins4(tb, code, q0[1], j0[1], q1[1], j1[1], q2[1], j2[1], q3[1], j3[1]);
                }
            }
        }
        __syncthreads();
    }

    // lane <-> lane+32 merge (same zrow, complementary code sets)
#pragma unroll
    for (int s = 0; s < 2; s++) {
        float ot0 = __shfl_xor(q0[s], 32), ot1 = __shfl_xor(q1[s], 32),
              ot2 = __shfl_xor(q2[s], 32), ot3 = __shfl_xor(q3[s], 32);
        int oi0 = __shfl_xor(j0[s], 32), oi1 = __shfl_xor(j1[s], 32),
            oi2 = __shfl_xor(j2[s], 32), oi3 = __shfl_xor(j3[s], 32);
        ins4(ot0, oi0, q0[s], j0[s], q1[s], j1[s], q2[s], j2[s], q3[s], j3[s]);
        ins4(ot1, oi1, q0[s], j0[s], q1[s], j1[s], q2[s], j2[s], q3[s], j3[s]);
        ins4(ot2, oi2, q0[s], j0[s], q1[s], j1[s], q2[s], j2[s], q3[s], j3[s]);
        ins4(ot3, oi3, q0[s], j0[s], q1[s], j1[s], q2[s], j2[s], q3[s], j3[s]);
    }

    __syncthreads();
    if (wave_m == 1 && lane < 32) {
#pragma unroll
        for (int s = 0; s < 2; s++) {
            int zr = wave_n * 64 + s * 32 + l31;
            mbuf[zr][0] = q0[s]; mbuf[zr][1] = q1[s]; mbuf[zr][2] = q2[s]; mbuf[zr][3] = q3[s];
            mbuf[zr][4] = __int_as_float(j0[s]); mbuf[zr][5] = __int_as_float(j1[s]);
            mbuf[zr][6] = __int_as_float(j2[s]); mbuf[zr][7] = __int_as_float(j3[s]);
        }
    }
    __syncthreads();
    if (wave_m == 0 && lane < 32) {
#pragma unroll
        for (int s = 0; s < 2; s++) {
            int zr = wave_n * 64 + s * 32 + l31;
            ins4(mbuf[zr][0], __float_as_int(mbuf[zr][4]),
                 q0[s], j0[s], q1[s], j1[s], q2[s], j2[s], q3[s], j3[s]);
            ins4(mbuf[zr][1], __float_as_int(mbuf[zr][5]),
                 q0[s], j0[s], q1[s], j1[s], q2[s], j2[s], q3[s], j3[s]);
            ins4(mbuf[zr][2], __float_as_int(mbuf[zr][6]),
                 q0[s], j0[s], q1[s], j1[s], q2[s], j2[s], q3[s], j3[s]);
            ins4(mbuf[zr][3], __float_as_int(mbuf[zr][7]),
                 q0[s], j0[s], q1[s], j1[s], q2[s], j2[s], q3[s], j3[s]);
            float4 pa = make_float4(q0[s], q1[s], q2[s], q3[s]);
            float4 pb = make_float4(__int_as_float(j0[s]), __int_as_float(j1[s]),
                                    __int_as_float(j2[s]), __int_as_float(j3[s]));
            size_t base = ((size_t)(brow0 + zr) * 8 + jg) * 2;
            part[base] = pa;
            part[base + 1] = pb;
        }
    }
}

// ---------------------------------------------------------------- fp64 rescore, wave-per-row (R5-validated)
__global__ void rescore_kernel(const float* __restrict__ z, const float* __restrict__ emb,
                               const float* __restrict__ enorm_g, const float* __restrict__ cnorm_g,
                               const float4* __restrict__ part, float* __restrict__ out,
                               int* __restrict__ ws_i0, int* __restrict__ hist,
                               double* __restrict__ t0sum) {
    const int tid  = threadIdx.x;
    const int lane = tid & 63, wid = tid >> 6;
    const int r = blockIdx.x * 4 + wid;       // 4096 blocks x 4 waves
    const int b = r >> 10, hw = r & 1023;
    const float* zb = z + ((size_t)b << 18) + hw;

    const int c4 = lane * 4;
    const double zv0 = (double)zb[(size_t)(c4 + 0) << 10];
    const double zv1 = (double)zb[(size_t)(c4 + 1) << 10];
    const double zv2 = (double)zb[(size_t)(c4 + 2) << 10];
    const double zv3 = (double)zb[(size_t)(c4 + 3) << 10];

    float m1 = FLT_MAX, m2 = FLT_MAX;
    for (int jg = 0; jg < 8; jg++) {
        float4 pa = part[((size_t)r * 8 + jg) * 2];
        if (pa.x < m1) { m2 = m1; m1 = pa.x; } else if (pa.x < m2) m2 = pa.x;
        if (pa.y < m1) { m2 = m1; m1 = pa.y; } else if (pa.y < m2) m2 = pa.y;
    }
    const float T = m2 + 1.2e-4f;
    const float C = cnorm_g[r];

    float bt0 = FLT_MAX, bt1 = FLT_MAX;
    int   bi0 = NE - 1, bi1 = NE - 1;
    bool  any = false;
    for (int jg = 0; jg < 8; jg++) {
        float4 pa = part[((size_t)r * 8 + jg) * 2];
        float4 pb = part[((size_t)r * 8 + jg) * 2 + 1];
        float tv[4] = {pa.x, pa.y, pa.z, pa.w};
        int   jv[4] = {__float_as_int(pb.x), __float_as_int(pb.y),
                       __float_as_int(pb.z), __float_as_int(pb.w)};
        for (int e = 0; e < 4; e++) {
            if (tv[e] <= T) {
                const int j = jv[e] & (NE - 1);
                const float* er = emb + ((size_t)j << 8);
                float4 ev = *(const float4*)(er + c4);
                double gl = zv0 * (double)ev.x + zv1 * (double)ev.y +
                            zv2 * (double)ev.z + zv3 * (double)ev.w;
#pragma unroll
                for (int m = 1; m < 64; m <<= 1) gl += __shfl_xor(gl, m);
                float g2 = (float)(2.0 * gl);
                float S = C + enorm_g[j];
                float tex = S - g2;
                if (tex < bt0 || (tex == bt0 && j < bi0)) {
                    bt1 = bt0; bi1 = bi0; bt0 = tex; bi0 = j;
                } else if (tex < bt1 || (tex == bt1 && j < bi1)) {
                    bt1 = tex; bi1 = j;
                }
                any = true;
            }
        }
    }
    if (!any) { bt0 = 0.f; bi0 = 0; bi1 = 0; }

    if (lane == 0) {
        out[OFF_I0 + r] = (float)bi0;
        out[OFF_I1 + r] = (float)bi1;
        ws_i0[r] = bi0;
        atomicAdd(&hist[bi0], 1);
    }
    __shared__ double red[4];
    if (lane == 0) red[wid] = (double)bt0;
    __syncthreads();
    if (tid == 0) atomicAdd(t0sum, (red[0] + red[1]) + (red[2] + red[3]));
}

// ---------------------------------------------------------------- z_q gather
__global__ void zq_kernel(const float* __restrict__ emb, const int* __restrict__ ws_i0,
                          float* __restrict__ out) {
    int bc = blockIdx.x;              // 4096 = 16 b * 256 c
    int bb = bc >> 8, c = bc & 255;
    int hwb = threadIdx.x * 4;
    const int4 iv = *(const int4*)(ws_i0 + bb * 1024 + hwb);
    float* op = out + OFF_ZQ + ((size_t)bc << 10) + hwb;
    op[0] = emb[(size_t)(iv.x & (NE - 1)) * KD + c];
    op[1] = emb[(size_t)(iv.y & (NE - 1)) * KD + c];
    op[2] = emb[(size_t)(iv.z & (NE - 1)) * KD + c];
    op[3] = emb[(size_t)(iv.w & (NE - 1)) * KD + c];
}

// ---------------------------------------------------------------- finalize
__global__ void finalize_kernel(const int* __restrict__ hist, const double* __restrict__ t0sum,
                                float* __restrict__ out) {
    __shared__ float red[256];
    float s = 0.f;
    for (int j = threadIdx.x; j < NE; j += 256) {
        float p = (float)hist[j] * (1.0f / 16384.0f);
        s += p * logf(p + 1e-10f);
    }
    red[threadIdx.x] = s;
    __syncthreads();
    for (int m = 128; m; m >>= 1) {
        if (threadIdx.x < m) red[threadIdx.x] += red[threadIdx.x + m];
        __syncthreads();
    }
    if (threadIdx.x == 0) {
        out[OFF_PERP] = expf(-red[0]);
        out[OFF_LOSS] = 1.25f * (float)(t0sum[0] * (1.0 / 4194304.0));
    }
}

extern "C" void kernel_launch(void* const* d_in, const int* in_sizes, int n_in,
                              void* d_out, int out_size, void* d_ws, size_t ws_size,
                              hipStream_t stream) {
    const float* z   = (const float*)d_in[0];
    const float* emb = (const float*)d_in[1];
    float* out = (float*)d_out;
    float* ws  = (float*)d_ws;

    int*    ws_i0    = (int*)ws + WS_I0;
    int*    ws_hist  = (int*)ws + WS_HIST;
    float*  ws_enorm = ws + WS_ENORM;
    float*  ws_cnorm = ws + WS_CNORM;
    double* ws_t0sum = (double*)(ws + WS_T0SUM);

    float* scr = out + OFF_ONEHOT + 2;   // 16B-aligned scratch in one-hot region
    _Float16* z16 = (_Float16*)(scr + SCR_Z16);
    _Float16* e16 = (_Float16*)(scr + SCR_E16);
    float4* part = (float4*)(scr + SCR_PART);

    hipLaunchKernelGGL(zero_ws_kernel, dim3(194), dim3(256), 0, stream, ws);
    hipLaunchKernelGGL(enorm_kernel, dim3(512), dim3(256), 0, stream, emb, ws_enorm);
    hipLaunchKernelGGL(cnorm_kernel, dim3(1024), dim3(256), 0, stream, z, ws_cnorm);
    hipLaunchKernelGGL(split_z_kernel, dim3(256, 4), dim3(256), 0, stream, z, z16);
    hipLaunchKernelGGL(split_e_kernel, dim3(1024), dim3(256), 0, stream, emb, e16);
    hipLaunchKernelGGL(mfma_top4_kernel, dim3(128, 8), dim3(256), 0, stream,
                       e16, z16, ws_enorm, ws_cnorm, part);
    hipLaunchKernelGGL(rescore_kernel, dim3(4096), dim3(256), 0, stream,
                       z, emb, ws_enorm, ws_cnorm, part, out, ws_i0, ws_hist, ws_t0sum);
    hipLaunchKernelGGL(zero_onehot_kernel, dim3(4096), dim3(1024), 0, stream, out);
    hipLaunchKernelGGL(scatter_ones_kernel, dim3(64), dim3(256), 0, stream, ws_i0, out);
    hipLaunchKernelGGL(zq_kernel, dim3(4096), dim3(256), 0, stream, emb, ws_i0, out);
    hipLaunchKernelGGL(finalize_kernel, dim3(1), dim3(256), 0, stream,
                       ws_hist, ws_t0sum, out);
}